// Round 10
// baseline (480.750 us; speedup 1.0000x reference)
//
#include <hip/hip_runtime.h>
#include <math.h>

#define NN_   6000
#define EE_   192000
#define CIN_  32
#define CHID_ 64
#define KK_   125   // 5^3 spline kernel cells
#define EB_   64    // edge batch per block in build_T
#define CH1_  8     // split-K chunks, x-GEMM (steps=125, spc=16)
#define SPC1_ 16
#define CH2_  8     // split-K chunks, h-GEMM (steps=250, spc=32)
#define SPC2_ 32

// fp32 -> bf16 round-to-nearest-even
static __device__ __forceinline__ unsigned short f2bf(float f) {
    unsigned int u = __builtin_bit_cast(unsigned int, f);
    u += 0x7fff + ((u >> 16) & 1);
    return (unsigned short)(u >> 16);
}
static __device__ __forceinline__ float bf2f(unsigned short h) {
    unsigned int u = ((unsigned int)h) << 16;
    return __builtin_bit_cast(float, u);
}

// ---------------------------------------------------------------------------
// Bucketing: counting sort of edges by dst, with precomputed edge records.
// ---------------------------------------------------------------------------
__global__ __launch_bounds__(256) void count_deg_kernel(
    const int* __restrict__ ei, int* __restrict__ deg)
{
    int e = blockIdx.x * 256 + threadIdx.x;
    if (e < EE_) atomicAdd(&deg[ei[EE_ + e]], 1);
}

__global__ __launch_bounds__(1024) void scan_kernel(
    const int* __restrict__ deg, int* __restrict__ offs, int* __restrict__ cursor)
{
    __shared__ int part[1024];
    const int tid = threadIdx.x;
    const int CH = (NN_ + 1023) / 1024;   // 6
    const int base = tid * CH;
    int loc[CH];
    int s = 0;
#pragma unroll
    for (int i = 0; i < CH; ++i) {
        int v = (base + i < NN_) ? deg[base + i] : 0;
        loc[i] = s; s += v;
    }
    part[tid] = s;
    __syncthreads();
    for (int off = 1; off < 1024; off <<= 1) {
        int v = (tid >= off) ? part[tid - off] : 0;
        __syncthreads();
        part[tid] += v;
        __syncthreads();
    }
    const int pre = (tid > 0) ? part[tid - 1] : 0;
#pragma unroll
    for (int i = 0; i < CH; ++i) {
        if (base + i < NN_) {
            offs[base + i]   = pre + loc[i];
            cursor[base + i] = pre + loc[i];
        }
    }
    if (tid == 1023) offs[NN_] = part[1023];
}

// Compute per-edge spline meta ONCE, scattered to dst-sorted position.
__global__ __launch_bounds__(256) void prep_kernel(
    const int* __restrict__ ei, const float* __restrict__ attr,
    int* __restrict__ cursor, float4* __restrict__ meta_s, int* __restrict__ src_s)
{
    int e = blockIdx.x * 256 + threadIdx.x;
    if (e >= EE_) return;
    const int dst = ei[EE_ + e];
    const int p   = atomicAdd(&cursor[dst], 1);
    float f[3]; int i0[3];
#pragma unroll
    for (int d = 0; d < 3; ++d) {
        float u  = attr[e * 3 + d] * 4.0f;
        float fl = floorf(u);
        fl = fminf(fmaxf(fl, 0.0f), 3.0f);
        i0[d] = (int)fl;
        f[d]  = u - fl;
    }
    meta_s[p] = make_float4(f[0], f[1], f[2],
        __int_as_float(i0[0] * 25 + i0[1] * 5 + i0[2]));
    src_s[p] = ei[e];
}

// ---------------------------------------------------------------------------
// Per-node T build, non-atomic (waves own disjoint channel-pairs -> plain
// b64 LDS RMW). Edge meta read coalesced from sorted records.
// ---------------------------------------------------------------------------
template<int C>
__global__ __launch_bounds__(256) void build_T_kernel(
    const float4* __restrict__ meta_s, const int* __restrict__ src_s,
    const float* __restrict__ feat, const int* __restrict__ offs,
    unsigned short* __restrict__ Tb)
{
    constexpr int PAD   = C + 2;
    constexpr int NPAIR = C / 2;
    constexpr int PPW   = NPAIR / 4;
    __shared__ float  Tl[KK_ * PAD];
    __shared__ float4 s_meta[EB_];
    __shared__ int    s_src[EB_];
    __shared__ float  s_feat[EB_ * C];

    const int node = blockIdx.x;
    const int tid  = threadIdx.x;
    const int wave = tid >> 6;
    const int lane = tid & 63;

    for (int i = tid; i < KK_ * PAD; i += 256) Tl[i] = 0.f;

    const int j0 = offs[node], j1 = offs[node + 1];

    const int  s_c  = lane / PPW;
    const int  pl   = lane % PPW;
    const int  pidx = wave * PPW + pl;
    const bool act  = lane < 8 * PPW;
    const int  cb0 = s_c & 1, cb1 = (s_c >> 1) & 1, cb2 = (s_c >> 2) & 1;
    const int  offc = cb0 * 25 + cb1 * 5 + cb2;

    __syncthreads();

    for (int jb = j0; jb < j1; jb += EB_) {
        const int m = min(EB_, j1 - jb);

        if (tid < m) {
            s_meta[tid] = meta_s[jb + tid];
            s_src[tid]  = src_s[jb + tid];
        }
        __syncthreads();

        constexpr int F4R = C / 4;
        for (int u = tid; u < m * F4R; u += 256) {
            int r = u / F4R, q = u % F4R;
            *(float4*)&s_feat[r * C + q * 4] =
                *(const float4*)&feat[(size_t)s_src[r] * C + q * 4];
        }
        __syncthreads();

        if (act) {
            for (int eb = 0; eb < m; ++eb) {
                const float4 mt = s_meta[eb];
                const int base  = __float_as_int(mt.w);
                const float p = (cb0 ? mt.x : 1.f - mt.x) *
                                (cb1 ? mt.y : 1.f - mt.y) *
                                (cb2 ? mt.z : 1.f - mt.z);
                const float2 fv = *(const float2*)&s_feat[eb * C + 2 * pidx];
                float* cell = &Tl[(base + offc) * PAD + 2 * pidx];
                cell[0] += p * fv.x;
                cell[1] += p * fv.y;
            }
        }
        __syncthreads();
    }

    unsigned int* To = (unsigned int*)(Tb + (size_t)node * (KK_ * C));
    for (int u = tid; u < KK_ * NPAIR; u += 256) {
        int k = u / NPAIR, pp = u % NPAIR;
        unsigned int lo = f2bf(Tl[k * PAD + 2 * pp]);
        unsigned int hi = f2bf(Tl[k * PAD + 2 * pp + 1]);
        To[u] = lo | (hi << 16);
    }
}

// ---------------------------------------------------------------------------
// Pack weights into transposed bf16 B matrices: Bt[n][k], n = conv*64 + o.
// ---------------------------------------------------------------------------
__global__ void pack_x_kernel(const float* __restrict__ Wa,
                              const float* __restrict__ Wb,
                              const float* __restrict__ Wc,
                              unsigned short* __restrict__ B1t)
{
    int gid = blockIdx.x * 256 + threadIdx.x;
    if (gid >= 192 * (KK_ * CIN_)) return;
    int n  = gid / (KK_ * CIN_);
    int kk = gid % (KK_ * CIN_);
    int conv = n >> 6, o = n & 63;
    const float* W = (conv == 0) ? Wa : ((conv == 1) ? Wb : Wc);
    B1t[gid] = f2bf(W[(size_t)kk * 64 + o]);
}

__global__ void pack_h_kernel(const float* __restrict__ Wa,
                              const float* __restrict__ Wb,
                              unsigned short* __restrict__ B2t)
{
    int gid = blockIdx.x * 256 + threadIdx.x;
    if (gid >= 128 * (KK_ * CHID_)) return;
    int n  = gid / (KK_ * CHID_);
    int kk = gid % (KK_ * CHID_);
    int conv = n >> 6, o = n & 63;
    const float* W = (conv == 0) ? Wa : Wb;
    B2t[gid] = f2bf(W[(size_t)kk * 64 + o]);
}

// ---------------------------------------------------------------------------
// MFMA bf16 GEMM, split-K, BM=32 (188 m-tiles -> ~6 blocks/CU at ch=8).
// Wave = (row-group rg, n-half nh): 1 A-frag + NFRAG B-frags per step.
// C-tile staged in LDS as bf16 (aliases Bs after barrier), then written with
// fully-coalesced uint4 stores -> full-sector HBM writes (R9's masked 4B
// stores caused 5x write amplification: 95 MB for 18 MB of partials).
// ---------------------------------------------------------------------------
template<int NT, int SPC>
__global__ __launch_bounds__(256) void mfma_gemm(
    const unsigned short* __restrict__ A, const unsigned short* __restrict__ Bt,
    unsigned short* __restrict__ P, int M, int Kd)
{
    constexpr int NH    = NT / 2;        // n-cols per wave pair: 96 / 64
    constexpr int NFRAG = NH / 16;       // B-frags per wave: 6 / 4
    constexpr int BLD   = NT / 64;       // uint4 B-loads per thread per step
    constexpr int CSP   = NT + 8;        // C-stage row pitch (16B-aligned rows)
    __shared__ unsigned short As[32][40];
    __shared__ unsigned short Bs[NT][40];  // reused as C-stage [32][CSP]

    using bf16x8 = __attribute__((ext_vector_type(8))) short;
    using f32x4  = __attribute__((ext_vector_type(4))) float;

    const int tid  = threadIdx.x;
    const int wave = tid >> 6;
    const int lane = tid & 63;
    const int quad = lane >> 4;
    const int l16  = lane & 15;
    const int rg   = wave & 1;           // row-group (16 rows)
    const int nh   = wave >> 1;          // n-half
    const int m0   = blockIdx.x * 32;
    const int chunk = blockIdx.y;

    const int steps = Kd >> 5;
    const int s0 = chunk * SPC;
    const int s1 = min(steps, s0 + SPC);

    f32x4 acc[NFRAG];
#pragma unroll
    for (int f = 0; f < NFRAG; ++f) acc[f] = (f32x4){0.f, 0.f, 0.f, 0.f};

    // A loader: thread t -> row t>>3 (0..31), 4 cols at (t&7)*4 (uint2)
    const int  arow   = tid >> 3;
    const int  acol   = (tid & 7) * 4;
    const bool avalid = (m0 + arow) < M;
    const unsigned short* Aptr = A + (size_t)(avalid ? (m0 + arow) : 0) * Kd + acol;

    uint2 a_st = make_uint2(0u, 0u);
    uint4 b_st[BLD];
    if (avalid) a_st = *(const uint2*)(Aptr + (s0 << 5));
#pragma unroll
    for (int j = 0; j < BLD; ++j) {
        int u = tid + 256 * j;
        b_st[j] = *(const uint4*)(Bt + (size_t)(u >> 2) * Kd + (s0 << 5) + (u & 3) * 8);
    }

    for (int s = s0; s < s1; ++s) {
        __syncthreads();
        *(uint2*)&As[arow][acol] = a_st;
#pragma unroll
        for (int j = 0; j < BLD; ++j) {
            int u = tid + 256 * j;
            *(uint4*)&Bs[u >> 2][(u & 3) * 8] = b_st[j];
        }
        __syncthreads();
        if (s + 1 < s1) {
            if (avalid) a_st = *(const uint2*)(Aptr + ((s + 1) << 5));
#pragma unroll
            for (int j = 0; j < BLD; ++j) {
                int u = tid + 256 * j;
                b_st[j] = *(const uint4*)(Bt + (size_t)(u >> 2) * Kd + ((s + 1) << 5) + (u & 3) * 8);
            }
        }
        bf16x8 af = *(bf16x8*)&As[rg * 16 + l16][quad * 8];
#pragma unroll
        for (int f = 0; f < NFRAG; ++f) {
            bf16x8 bfv = *(bf16x8*)&Bs[nh * NH + f * 16 + l16][quad * 8];
            acc[f] = __builtin_amdgcn_mfma_f32_16x16x32_bf16(af, bfv, acc[f], 0, 0, 0);
        }
    }

    // stage C-tile in LDS (bf16), then fully-coalesced full-line global copy
    __syncthreads();
    unsigned short* Cs = &Bs[0][0];      // [32][CSP]
    const int rbase = rg * 16 + quad * 4;
#pragma unroll
    for (int f = 0; f < NFRAG; ++f) {
        const int col = nh * NH + f * 16 + l16;
#pragma unroll
        for (int r = 0; r < 4; ++r)
            Cs[(rbase + r) * CSP + col] = f2bf(acc[f][r]);
    }
    __syncthreads();
    unsigned short* Pc = P + ((size_t)chunk * M + m0) * NT;
    constexpr int UNITS = 32 * NT / 8;
    for (int u = tid; u < UNITS; u += 256) {
        const int row = (u * 8) / NT, col = (u * 8) % NT;
        if (m0 + row < M)
            *(uint4*)&Pc[(size_t)row * NT + col] = *(const uint4*)&Cs[row * CSP + col];
    }
}

// ---------------------------------------------------------------------------
// Epilogue: one wave per node, lane = output channel. Sums bf16 split-K
// partials (2B/lane coalesced, mostly L2-resident), mean-agg, root GEMV,
// GRU gates.
// ---------------------------------------------------------------------------
__global__ __launch_bounds__(256) void epilogue_kernel(
    const unsigned short* __restrict__ P1, const unsigned short* __restrict__ P2,
    const int* __restrict__ offs,
    const float* __restrict__ x, const float* __restrict__ hidden,
    const float* __restrict__ root_xr, const float* __restrict__ root_hr,
    const float* __restrict__ root_xz, const float* __restrict__ root_hz,
    const float* __restrict__ root_xn,
    const float* __restrict__ b_xr, const float* __restrict__ b_hr,
    const float* __restrict__ b_xz, const float* __restrict__ b_hz,
    const float* __restrict__ b_xn,
    float* __restrict__ out)
{
    __shared__ float xsh[4][32];
    __shared__ float hsh[4][64];
    const int w = threadIdx.x >> 6;
    const int o = threadIdx.x & 63;
    const int m = blockIdx.x * 4 + w;
    if (m >= NN_) return;

    if (o < 32) xsh[w][o] = x[(size_t)m * 32 + o];
    const float hval = hidden[(size_t)m * 64 + o];
    hsh[w][o] = hval;

    float axr = 0.f, axz = 0.f, axn = 0.f;
#pragma unroll
    for (int c = 0; c < CH1_; ++c) {
        const unsigned short* p = P1 + ((size_t)c * NN_ + m) * 192;
        axr += bf2f(p[o]); axz += bf2f(p[64 + o]); axn += bf2f(p[128 + o]);
    }
    float ahr = 0.f, ahz = 0.f;
#pragma unroll
    for (int c = 0; c < CH2_; ++c) {
        const unsigned short* p = P2 + ((size_t)c * NN_ + m) * 128;
        ahr += bf2f(p[o]); ahz += bf2f(p[64 + o]);
    }

    const int   dg   = offs[m + 1] - offs[m];
    const float dinv = 1.0f / fmaxf((float)dg, 1.0f);
    axr *= dinv; axz *= dinv; axn *= dinv; ahr *= dinv; ahz *= dinv;

    float sxr = 0.f, sxz = 0.f, sxn = 0.f;
#pragma unroll
    for (int c = 0; c < CIN_; ++c) {
        float xv = xsh[w][c];
        sxr += xv * root_xr[c * 64 + o];
        sxz += xv * root_xz[c * 64 + o];
        sxn += xv * root_xn[c * 64 + o];
    }
    float shr = 0.f, shz = 0.f;
#pragma unroll
    for (int c = 0; c < CHID_; ++c) {
        float hv = hsh[w][c];
        shr += hv * root_hr[c * 64 + o];
        shz += hv * root_hz[c * 64 + o];
    }

    const float conv_xr = axr + sxr + b_xr[o];
    const float conv_xz = axz + sxz + b_xz[o];
    const float conv_xn = axn + sxn + b_xn[o];
    const float hr_out  = ahr + shr + b_hr[o];
    const float conv_hz = ahz + shz + b_hz[o];

    const float rg = 1.0f / (1.0f + expf(-(conv_xr + hr_out)));
    const float zg = 1.0f / (1.0f + expf(-(conv_xz + conv_hz)));
    const float ng = tanhf(conv_xn + rg * hr_out);
    out[(size_t)m * 64 + o] = (1.0f - zg) * ng + zg * hval;
}

// ---------------------------------------------------------------------------
extern "C" void kernel_launch(void* const* d_in, const int* in_sizes, int n_in,
                              void* d_out, int out_size, void* d_ws, size_t ws_size,
                              hipStream_t stream)
{
    const float* x       = (const float*)d_in[0];
    const float* hidden  = (const float*)d_in[1];
    const int*   ei      = (const int*)  d_in[2];
    const float* attr    = (const float*)d_in[3];
    const float* W_xr    = (const float*)d_in[4];
    const float* root_xr = (const float*)d_in[5];
    const float* b_xr    = (const float*)d_in[6];
    const float* W_hr    = (const float*)d_in[7];
    const float* root_hr = (const float*)d_in[8];
    const float* b_hr    = (const float*)d_in[9];
    const float* W_xz    = (const float*)d_in[10];
    const float* root_xz = (const float*)d_in[11];
    const float* b_xz    = (const float*)d_in[12];
    const float* W_hz    = (const float*)d_in[13];
    const float* root_hz = (const float*)d_in[14];
    const float* b_hz    = (const float*)d_in[15];
    const float* W_xn    = (const float*)d_in[16];
    const float* root_xn = (const float*)d_in[17];
    const float* b_xn    = (const float*)d_in[18];
    // d_in[19..21] (W_hn/root_hn/b_hn) are dead: reference reuses hr_out.
    float* out = (float*)d_out;

    // Workspace (~183 MB)
    char* w = (char*)d_ws;
    unsigned short* Tx  = (unsigned short*)w; w += (size_t)NN_ * KK_ * CIN_  * 2;  // 48 MB
    unsigned short* Th  = (unsigned short*)w; w += (size_t)NN_ * KK_ * CHID_ * 2;  // 96 MB
    unsigned short* B1t = (unsigned short*)w; w += (size_t)192 * KK_ * CIN_  * 2;  // 1.5 MB
    unsigned short* B2t = (unsigned short*)w; w += (size_t)128 * KK_ * CHID_ * 2;  // 2.0 MB
    unsigned short* P1  = (unsigned short*)w; w += (size_t)CH1_ * NN_ * 192 * 2;   // 18.4 MB
    unsigned short* P2  = (unsigned short*)w; w += (size_t)CH2_ * NN_ * 128 * 2;   // 12.3 MB
    float4* meta_s = (float4*)w; w += (size_t)EE_ * 16;                            // 3.07 MB
    int* src_s  = (int*)w;   w += (size_t)EE_ * 4;                                 // 0.77 MB
    int* deg    = (int*)w;   w += (size_t)NN_ * 4;
    int* offs   = (int*)w;   w += (size_t)(NN_ + 4) * 4;
    int* cursor = (int*)w;   w += (size_t)NN_ * 4;

    const int MT2 = (NN_ + 31) / 32;   // 188 m-tiles (BM=32)

    hipMemsetAsync(deg, 0, (size_t)NN_ * 4, stream);

    // ---- bucket edges by dst + precompute sorted edge records ----
    count_deg_kernel<<<(EE_ + 255) / 256, 256, 0, stream>>>(ei, deg);
    scan_kernel<<<1, 1024, 0, stream>>>(deg, offs, cursor);
    prep_kernel<<<(EE_ + 255) / 256, 256, 0, stream>>>(ei, attr, cursor, meta_s, src_s);

    // ---- weight packs ----
    pack_x_kernel<<<(192 * KK_ * CIN_ + 255) / 256, 256, 0, stream>>>(W_xr, W_xz, W_xn, B1t);
    pack_h_kernel<<<(128 * KK_ * CHID_ + 255) / 256, 256, 0, stream>>>(W_hr, W_hz, B2t);

    // ---- non-atomic LDS T builds (coalesced sorted-record input) ----
    build_T_kernel<CIN_><<<NN_, 256, 0, stream>>>(meta_s, src_s, x, offs, Tx);
    build_T_kernel<CHID_><<<NN_, 256, 0, stream>>>(meta_s, src_s, hidden, offs, Th);

    // ---- GEMMs -> bf16 partials, LDS-staged full-line stores ----
    mfma_gemm<192, SPC1_><<<dim3(MT2, CH1_), 256, 0, stream>>>(Tx, B1t, P1, NN_, KK_ * CIN_);
    mfma_gemm<128, SPC2_><<<dim3(MT2, CH2_), 256, 0, stream>>>(Th, B2t, P2, NN_, KK_ * CHID_);

    // ---- fused reduce + GRU epilogue (wave per node) ----
    epilogue_kernel<<<(NN_ + 3) / 4, 256, 0, stream>>>(
        P1, P2, offs, x, hidden,
        root_xr, root_hr, root_xz, root_hz, root_xn,
        b_xr, b_hr, b_xz, b_hz, b_xn, out);
}

// Round 11
// 395.746 us; speedup vs baseline: 1.2148x; 1.2148x over previous
//
#include <hip/hip_runtime.h>
#include <math.h>

#define NN_   6000
#define EE_   192000
#define CIN_  32
#define CHID_ 64
#define KK_   125   // 5^3 spline kernel cells
#define EB_   64    // edge batch per block in build_T
#define CH1_  10    // split-K chunks, x-GEMM (steps=125, spc=13)
#define SPC1_ 13
#define CH2_  12    // split-K chunks, h-GEMM (steps=250, spc=21)
#define SPC2_ 21

// fp32 -> bf16 round-to-nearest-even
static __device__ __forceinline__ unsigned short f2bf(float f) {
    unsigned int u = __builtin_bit_cast(unsigned int, f);
    u += 0x7fff + ((u >> 16) & 1);
    return (unsigned short)(u >> 16);
}
static __device__ __forceinline__ float bf2f(unsigned short h) {
    unsigned int u = ((unsigned int)h) << 16;
    return __builtin_bit_cast(float, u);
}

// ---------------------------------------------------------------------------
// Bucketing: counting sort of edges by dst, with precomputed edge records.
// ---------------------------------------------------------------------------
__global__ __launch_bounds__(256) void count_deg_kernel(
    const int* __restrict__ ei, int* __restrict__ deg)
{
    int e = blockIdx.x * 256 + threadIdx.x;
    if (e < EE_) atomicAdd(&deg[ei[EE_ + e]], 1);
}

__global__ __launch_bounds__(1024) void scan_kernel(
    const int* __restrict__ deg, int* __restrict__ offs, int* __restrict__ cursor)
{
    __shared__ int part[1024];
    const int tid = threadIdx.x;
    const int CH = (NN_ + 1023) / 1024;   // 6
    const int base = tid * CH;
    int loc[CH];
    int s = 0;
#pragma unroll
    for (int i = 0; i < CH; ++i) {
        int v = (base + i < NN_) ? deg[base + i] : 0;
        loc[i] = s; s += v;
    }
    part[tid] = s;
    __syncthreads();
    for (int off = 1; off < 1024; off <<= 1) {
        int v = (tid >= off) ? part[tid - off] : 0;
        __syncthreads();
        part[tid] += v;
        __syncthreads();
    }
    const int pre = (tid > 0) ? part[tid - 1] : 0;
#pragma unroll
    for (int i = 0; i < CH; ++i) {
        if (base + i < NN_) {
            offs[base + i]   = pre + loc[i];
            cursor[base + i] = pre + loc[i];
        }
    }
    if (tid == 1023) offs[NN_] = part[1023];
}

// Compute per-edge spline meta ONCE, scattered to dst-sorted position.
__global__ __launch_bounds__(256) void prep_kernel(
    const int* __restrict__ ei, const float* __restrict__ attr,
    int* __restrict__ cursor, float4* __restrict__ meta_s, int* __restrict__ src_s)
{
    int e = blockIdx.x * 256 + threadIdx.x;
    if (e >= EE_) return;
    const int dst = ei[EE_ + e];
    const int p   = atomicAdd(&cursor[dst], 1);
    float f[3]; int i0[3];
#pragma unroll
    for (int d = 0; d < 3; ++d) {
        float u  = attr[e * 3 + d] * 4.0f;
        float fl = floorf(u);
        fl = fminf(fmaxf(fl, 0.0f), 3.0f);
        i0[d] = (int)fl;
        f[d]  = u - fl;
    }
    meta_s[p] = make_float4(f[0], f[1], f[2],
        __int_as_float(i0[0] * 25 + i0[1] * 5 + i0[2]));
    src_s[p] = ei[e];
}

// ---------------------------------------------------------------------------
// Per-node T build, non-atomic (waves own disjoint channel-pairs -> plain
// b64 LDS RMW). Edge meta read coalesced from sorted records.
// ---------------------------------------------------------------------------
template<int C>
__global__ __launch_bounds__(256) void build_T_kernel(
    const float4* __restrict__ meta_s, const int* __restrict__ src_s,
    const float* __restrict__ feat, const int* __restrict__ offs,
    unsigned short* __restrict__ Tb)
{
    constexpr int PAD   = C + 2;
    constexpr int NPAIR = C / 2;
    constexpr int PPW   = NPAIR / 4;
    __shared__ float  Tl[KK_ * PAD];
    __shared__ float4 s_meta[EB_];
    __shared__ int    s_src[EB_];
    __shared__ float  s_feat[EB_ * C];

    const int node = blockIdx.x;
    const int tid  = threadIdx.x;
    const int wave = tid >> 6;
    const int lane = tid & 63;

    for (int i = tid; i < KK_ * PAD; i += 256) Tl[i] = 0.f;

    const int j0 = offs[node], j1 = offs[node + 1];

    const int  s_c  = lane / PPW;
    const int  pl   = lane % PPW;
    const int  pidx = wave * PPW + pl;
    const bool act  = lane < 8 * PPW;
    const int  cb0 = s_c & 1, cb1 = (s_c >> 1) & 1, cb2 = (s_c >> 2) & 1;
    const int  offc = cb0 * 25 + cb1 * 5 + cb2;

    __syncthreads();

    for (int jb = j0; jb < j1; jb += EB_) {
        const int m = min(EB_, j1 - jb);

        if (tid < m) {
            s_meta[tid] = meta_s[jb + tid];
            s_src[tid]  = src_s[jb + tid];
        }
        __syncthreads();

        constexpr int F4R = C / 4;
        for (int u = tid; u < m * F4R; u += 256) {
            int r = u / F4R, q = u % F4R;
            *(float4*)&s_feat[r * C + q * 4] =
                *(const float4*)&feat[(size_t)s_src[r] * C + q * 4];
        }
        __syncthreads();

        if (act) {
            for (int eb = 0; eb < m; ++eb) {
                const float4 mt = s_meta[eb];
                const int base  = __float_as_int(mt.w);
                const float p = (cb0 ? mt.x : 1.f - mt.x) *
                                (cb1 ? mt.y : 1.f - mt.y) *
                                (cb2 ? mt.z : 1.f - mt.z);
                const float2 fv = *(const float2*)&s_feat[eb * C + 2 * pidx];
                float* cell = &Tl[(base + offc) * PAD + 2 * pidx];
                cell[0] += p * fv.x;
                cell[1] += p * fv.y;
            }
        }
        __syncthreads();
    }

    unsigned int* To = (unsigned int*)(Tb + (size_t)node * (KK_ * C));
    for (int u = tid; u < KK_ * NPAIR; u += 256) {
        int k = u / NPAIR, pp = u % NPAIR;
        unsigned int lo = f2bf(Tl[k * PAD + 2 * pp]);
        unsigned int hi = f2bf(Tl[k * PAD + 2 * pp + 1]);
        To[u] = lo | (hi << 16);
    }
}

// ---------------------------------------------------------------------------
// Pack weights into transposed bf16 B matrices: Bt[n][k], n = conv*64 + o.
// ---------------------------------------------------------------------------
__global__ void pack_x_kernel(const float* __restrict__ Wa,
                              const float* __restrict__ Wb,
                              const float* __restrict__ Wc,
                              unsigned short* __restrict__ B1t)
{
    int gid = blockIdx.x * 256 + threadIdx.x;
    if (gid >= 192 * (KK_ * CIN_)) return;
    int n  = gid / (KK_ * CIN_);
    int kk = gid % (KK_ * CIN_);
    int conv = n >> 6, o = n & 63;
    const float* W = (conv == 0) ? Wa : ((conv == 1) ? Wb : Wc);
    B1t[gid] = f2bf(W[(size_t)kk * 64 + o]);
}

__global__ void pack_h_kernel(const float* __restrict__ Wa,
                              const float* __restrict__ Wb,
                              unsigned short* __restrict__ B2t)
{
    int gid = blockIdx.x * 256 + threadIdx.x;
    if (gid >= 128 * (KK_ * CHID_)) return;
    int n  = gid / (KK_ * CHID_);
    int kk = gid % (KK_ * CHID_);
    int conv = n >> 6, o = n & 63;
    const float* W = (conv == 0) ? Wa : Wb;
    B2t[gid] = f2bf(W[(size_t)kk * 64 + o]);
}

// ---------------------------------------------------------------------------
// MFMA bf16 GEMM, split-K, BM=64 (R9's proven tile: best B-reuse), VGPR
// prefetch staging. C-tile staged in LDS as bf16 (aliases the As/Bs arena
// after a barrier), then written with fully-coalesced uint4 stores.
// BM=32 (R10) halved B-reuse and regressed; masked 4B stores (R9) wasted
// store bandwidth. This combines the best of both.
// ---------------------------------------------------------------------------
template<int NT, int SPC>
__global__ __launch_bounds__(256) void mfma_gemm(
    const unsigned short* __restrict__ A, const unsigned short* __restrict__ Bt,
    unsigned short* __restrict__ P, int M, int Kd)
{
    constexpr int NFRAG = NT / 16;       // B-frags per wave: 12 / 8
    constexpr int BLD   = NT / 64;       // uint4 B-loads per thread per step
    constexpr int CSP   = NT + 8;        // C-stage row pitch (shorts)
    constexpr int SM_AB = 64 * 80 + NT * 80;          // As + Bs bytes
    constexpr int SM_C  = 64 * CSP * 2;               // C-stage bytes
    constexpr int SMEM  = SM_AB > SM_C ? SM_AB : SM_C;
    __shared__ unsigned char smem[SMEM];
    unsigned short (*As)[40] = (unsigned short(*)[40])smem;
    unsigned short (*Bs)[40] = (unsigned short(*)[40])(smem + 64 * 80);
    unsigned short* Cs       = (unsigned short*)smem;

    using bf16x8 = __attribute__((ext_vector_type(8))) short;
    using f32x4  = __attribute__((ext_vector_type(4))) float;

    const int tid  = threadIdx.x;
    const int wave = tid >> 6;
    const int lane = tid & 63;
    const int quad = lane >> 4;
    const int l16  = lane & 15;
    const int m0   = blockIdx.x * 64;
    const int chunk = blockIdx.y;

    const int steps = Kd >> 5;
    const int s0 = chunk * SPC;
    const int s1 = min(steps, s0 + SPC);

    f32x4 acc[NFRAG];
#pragma unroll
    for (int f = 0; f < NFRAG; ++f) acc[f] = (f32x4){0.f, 0.f, 0.f, 0.f};

    const int  arow   = tid >> 2;
    const int  acol   = (tid & 3) * 8;
    const bool avalid = (m0 + arow) < M;
    const unsigned short* Aptr = A + (size_t)(avalid ? (m0 + arow) : 0) * Kd + acol;

    uint4 a_st = make_uint4(0u, 0u, 0u, 0u);
    uint4 b_st[BLD];
    if (avalid) a_st = *(const uint4*)(Aptr + (s0 << 5));
#pragma unroll
    for (int j = 0; j < BLD; ++j) {
        int u = tid + 256 * j;
        b_st[j] = *(const uint4*)(Bt + (size_t)(u >> 2) * Kd + (s0 << 5) + (u & 3) * 8);
    }

    for (int s = s0; s < s1; ++s) {
        __syncthreads();
        *(uint4*)&As[arow][acol] = a_st;
#pragma unroll
        for (int j = 0; j < BLD; ++j) {
            int u = tid + 256 * j;
            *(uint4*)&Bs[u >> 2][(u & 3) * 8] = b_st[j];
        }
        __syncthreads();
        if (s + 1 < s1) {
            if (avalid) a_st = *(const uint4*)(Aptr + ((s + 1) << 5));
#pragma unroll
            for (int j = 0; j < BLD; ++j) {
                int u = tid + 256 * j;
                b_st[j] = *(const uint4*)(Bt + (size_t)(u >> 2) * Kd + ((s + 1) << 5) + (u & 3) * 8);
            }
        }
        bf16x8 af = *(bf16x8*)&As[wave * 16 + l16][quad * 8];
#pragma unroll
        for (int f = 0; f < NFRAG; ++f) {
            bf16x8 bfv = *(bf16x8*)&Bs[f * 16 + l16][quad * 8];
            acc[f] = __builtin_amdgcn_mfma_f32_16x16x32_bf16(af, bfv, acc[f], 0, 0, 0);
        }
    }

    // stage C-tile (bf16) in the LDS arena, then full-line coalesced copy out
    __syncthreads();
    const int rbase = wave * 16 + quad * 4;
#pragma unroll
    for (int f = 0; f < NFRAG; ++f) {
        const int col = f * 16 + l16;
#pragma unroll
        for (int r = 0; r < 4; ++r)
            Cs[(rbase + r) * CSP + col] = f2bf(acc[f][r]);
    }
    __syncthreads();
    unsigned short* Pc = P + ((size_t)chunk * M + m0) * NT;
    constexpr int UNITS = 64 * NT / 8;
    for (int u = tid; u < UNITS; u += 256) {
        const int row = (u * 8) / NT, col = (u * 8) % NT;
        if (m0 + row < M)
            *(uint4*)&Pc[(size_t)row * NT + col] = *(const uint4*)&Cs[row * CSP + col];
    }
}

// ---------------------------------------------------------------------------
// Epilogue: one wave per node, lane = output channel. Sums bf16 split-K
// partials (2B/lane coalesced), mean-agg, root GEMV, GRU gates.
// ---------------------------------------------------------------------------
__global__ __launch_bounds__(256) void epilogue_kernel(
    const unsigned short* __restrict__ P1, const unsigned short* __restrict__ P2,
    const int* __restrict__ offs,
    const float* __restrict__ x, const float* __restrict__ hidden,
    const float* __restrict__ root_xr, const float* __restrict__ root_hr,
    const float* __restrict__ root_xz, const float* __restrict__ root_hz,
    const float* __restrict__ root_xn,
    const float* __restrict__ b_xr, const float* __restrict__ b_hr,
    const float* __restrict__ b_xz, const float* __restrict__ b_hz,
    const float* __restrict__ b_xn,
    float* __restrict__ out)
{
    __shared__ float xsh[4][32];
    __shared__ float hsh[4][64];
    const int w = threadIdx.x >> 6;
    const int o = threadIdx.x & 63;
    const int m = blockIdx.x * 4 + w;
    if (m >= NN_) return;

    if (o < 32) xsh[w][o] = x[(size_t)m * 32 + o];
    const float hval = hidden[(size_t)m * 64 + o];
    hsh[w][o] = hval;

    float axr = 0.f, axz = 0.f, axn = 0.f;
#pragma unroll
    for (int c = 0; c < CH1_; ++c) {
        const unsigned short* p = P1 + ((size_t)c * NN_ + m) * 192;
        axr += bf2f(p[o]); axz += bf2f(p[64 + o]); axn += bf2f(p[128 + o]);
    }
    float ahr = 0.f, ahz = 0.f;
#pragma unroll
    for (int c = 0; c < CH2_; ++c) {
        const unsigned short* p = P2 + ((size_t)c * NN_ + m) * 128;
        ahr += bf2f(p[o]); ahz += bf2f(p[64 + o]);
    }

    const int   dg   = offs[m + 1] - offs[m];
    const float dinv = 1.0f / fmaxf((float)dg, 1.0f);
    axr *= dinv; axz *= dinv; axn *= dinv; ahr *= dinv; ahz *= dinv;

    float sxr = 0.f, sxz = 0.f, sxn = 0.f;
#pragma unroll
    for (int c = 0; c < CIN_; ++c) {
        float xv = xsh[w][c];
        sxr += xv * root_xr[c * 64 + o];
        sxz += xv * root_xz[c * 64 + o];
        sxn += xv * root_xn[c * 64 + o];
    }
    float shr = 0.f, shz = 0.f;
#pragma unroll
    for (int c = 0; c < CHID_; ++c) {
        float hv = hsh[w][c];
        shr += hv * root_hr[c * 64 + o];
        shz += hv * root_hz[c * 64 + o];
    }

    const float conv_xr = axr + sxr + b_xr[o];
    const float conv_xz = axz + sxz + b_xz[o];
    const float conv_xn = axn + sxn + b_xn[o];
    const float hr_out  = ahr + shr + b_hr[o];
    const float conv_hz = ahz + shz + b_hz[o];

    const float rg = 1.0f / (1.0f + expf(-(conv_xr + hr_out)));
    const float zg = 1.0f / (1.0f + expf(-(conv_xz + conv_hz)));
    const float ng = tanhf(conv_xn + rg * hr_out);
    out[(size_t)m * 64 + o] = (1.0f - zg) * ng + zg * hval;
}

// ---------------------------------------------------------------------------
extern "C" void kernel_launch(void* const* d_in, const int* in_sizes, int n_in,
                              void* d_out, int out_size, void* d_ws, size_t ws_size,
                              hipStream_t stream)
{
    const float* x       = (const float*)d_in[0];
    const float* hidden  = (const float*)d_in[1];
    const int*   ei      = (const int*)  d_in[2];
    const float* attr    = (const float*)d_in[3];
    const float* W_xr    = (const float*)d_in[4];
    const float* root_xr = (const float*)d_in[5];
    const float* b_xr    = (const float*)d_in[6];
    const float* W_hr    = (const float*)d_in[7];
    const float* root_hr = (const float*)d_in[8];
    const float* b_hr    = (const float*)d_in[9];
    const float* W_xz    = (const float*)d_in[10];
    const float* root_xz = (const float*)d_in[11];
    const float* b_xz    = (const float*)d_in[12];
    const float* W_hz    = (const float*)d_in[13];
    const float* root_hz = (const float*)d_in[14];
    const float* b_hz    = (const float*)d_in[15];
    const float* W_xn    = (const float*)d_in[16];
    const float* root_xn = (const float*)d_in[17];
    const float* b_xn    = (const float*)d_in[18];
    // d_in[19..21] (W_hn/root_hn/b_hn) are dead: reference reuses hr_out.
    float* out = (float*)d_out;

    // Workspace (~193 MB)
    char* w = (char*)d_ws;
    unsigned short* Tx  = (unsigned short*)w; w += (size_t)NN_ * KK_ * CIN_  * 2;  // 48 MB
    unsigned short* Th  = (unsigned short*)w; w += (size_t)NN_ * KK_ * CHID_ * 2;  // 96 MB
    unsigned short* B1t = (unsigned short*)w; w += (size_t)192 * KK_ * CIN_  * 2;  // 1.5 MB
    unsigned short* B2t = (unsigned short*)w; w += (size_t)128 * KK_ * CHID_ * 2;  // 2.0 MB
    unsigned short* P1  = (unsigned short*)w; w += (size_t)CH1_ * NN_ * 192 * 2;   // 23.0 MB
    unsigned short* P2  = (unsigned short*)w; w += (size_t)CH2_ * NN_ * 128 * 2;   // 18.4 MB
    float4* meta_s = (float4*)w; w += (size_t)EE_ * 16;                            // 3.07 MB
    int* src_s  = (int*)w;   w += (size_t)EE_ * 4;                                 // 0.77 MB
    int* deg    = (int*)w;   w += (size_t)NN_ * 4;
    int* offs   = (int*)w;   w += (size_t)(NN_ + 4) * 4;
    int* cursor = (int*)w;   w += (size_t)NN_ * 4;

    const int MT = (NN_ + 63) / 64;   // 94 m-tiles

    hipMemsetAsync(deg, 0, (size_t)NN_ * 4, stream);

    // ---- bucket edges by dst + precompute sorted edge records ----
    count_deg_kernel<<<(EE_ + 255) / 256, 256, 0, stream>>>(ei, deg);
    scan_kernel<<<1, 1024, 0, stream>>>(deg, offs, cursor);
    prep_kernel<<<(EE_ + 255) / 256, 256, 0, stream>>>(ei, attr, cursor, meta_s, src_s);

    // ---- weight packs ----
    pack_x_kernel<<<(192 * KK_ * CIN_ + 255) / 256, 256, 0, stream>>>(W_xr, W_xz, W_xn, B1t);
    pack_h_kernel<<<(128 * KK_ * CHID_ + 255) / 256, 256, 0, stream>>>(W_hr, W_hz, B2t);

    // ---- non-atomic LDS T builds (coalesced sorted-record input) ----
    build_T_kernel<CIN_><<<NN_, 256, 0, stream>>>(meta_s, src_s, x, offs, Tx);
    build_T_kernel<CHID_><<<NN_, 256, 0, stream>>>(meta_s, src_s, hidden, offs, Th);

    // ---- GEMMs -> bf16 partials, LDS-staged full-line stores ----
    mfma_gemm<192, SPC1_><<<dim3(MT, CH1_), 256, 0, stream>>>(Tx, B1t, P1, NN_, KK_ * CIN_);
    mfma_gemm<128, SPC2_><<<dim3(MT, CH2_), 256, 0, stream>>>(Th, B2t, P2, NN_, KK_ * CHID_);

    // ---- fused reduce + GRU epilogue (wave per node) ----
    epilogue_kernel<<<(NN_ + 3) / 4, 256, 0, stream>>>(
        P1, P2, offs, x, hidden,
        root_xr, root_hr, root_xz, root_hz, root_xn,
        b_xr, b_hr, b_xz, b_hz, b_xn, out);
}